// Round 6
// baseline (314.844 us; speedup 1.0000x reference)
//
#include <hip/hip_runtime.h>

// SelfAttention: B=4, S=2048, D=1024, H=16, Hd=64. f32 in/out, bf16 MFMA inside.

#define LOG2E 1.4426950408889634f
#define QSCALE (0.125f * LOG2E)   // 1/sqrt(64) * log2(e), folded into Wq/bq

typedef __bf16 bf16x8 __attribute__((ext_vector_type(8)));
typedef float f32x4 __attribute__((ext_vector_type(4)));
typedef unsigned short u16x4 __attribute__((ext_vector_type(4)));
typedef unsigned short u16x8 __attribute__((ext_vector_type(8)));
typedef unsigned int u32x4 __attribute__((ext_vector_type(4)));

__device__ __forceinline__ unsigned short f2bf(float f) {
  unsigned int u = __builtin_bit_cast(unsigned int, f);
  u += 0x7fffu + ((u >> 16) & 1u);   // RNE
  return (unsigned short)(u >> 16);
}

// pack bf16(a) low16, bf16(b) high16; RNE. v_bfe+v_add3 x2 + v_perm.
__device__ __forceinline__ unsigned int pack2bf(float a, float b) {
  unsigned int ua = __builtin_bit_cast(unsigned int, a);
  unsigned int ub = __builtin_bit_cast(unsigned int, b);
  ua += 0x7fffu + ((ua >> 16) & 1u);
  ub += 0x7fffu + ((ub >> 16) & 1u);
  return __builtin_amdgcn_perm(ub, ua, 0x07060302u);
}

typedef const __attribute__((address_space(1))) void* gptr_t;
typedef __attribute__((address_space(3))) void* lptr_t;
__device__ __forceinline__ void gload16(const void* g, void* l) {
  __builtin_amdgcn_global_load_lds((gptr_t)g, (lptr_t)l, 16, 0, 0);
}

// ---------------- merged convert kernel ----------------
// first 8388608 els: x -> xb; next 4194304: {Wq,Wk,Wv,Wo} -> Wb (Wq scaled).
__global__ __launch_bounds__(256) void k_cvt(const float* __restrict__ x,
                                             const float* __restrict__ Wq, const float* __restrict__ Wk,
                                             const float* __restrict__ Wv, const float* __restrict__ Wo,
                                             unsigned short* __restrict__ xb, unsigned short* __restrict__ Wb) {
  int gi = (blockIdx.x * 256 + threadIdx.x) * 4;
  if (gi < 8388608) {
    f32x4 v = *(const f32x4*)(x + gi);
    u16x4 o; o[0] = f2bf(v[0]); o[1] = f2bf(v[1]); o[2] = f2bf(v[2]); o[3] = f2bf(v[3]);
    *(u16x4*)(xb + gi) = o;
  } else {
    int i = gi - 8388608;
    int wsel = i >> 20;
    int loc = i & 1048575;
    const float* src = (wsel == 0) ? Wq : (wsel == 1) ? Wk : (wsel == 2) ? Wv : Wo;
    float sc = (wsel == 0) ? QSCALE : 1.0f;
    f32x4 v = *(const f32x4*)(src + loc);
    u16x4 o; o[0] = f2bf(v[0] * sc); o[1] = f2bf(v[1] * sc); o[2] = f2bf(v[2] * sc); o[3] = f2bf(v[3] * sc);
    *(u16x4*)(Wb + i) = o;
  }
}

// ---------------- QKV projection GEMM ----------------
// C[m][n] = sum_k x[m][k] * W[n][k] + b[n]; M=8192, N=1024, K=1024.
// z=0: Q (pre-scaled) -> [b,h,s,d]; z=1: K -> [b,h,s,d];
// z=2: V -> [b,h,d,s_perm]: key s at permuted pos (pos=8q+4h+r for s=16h+4q+r)
//      so flash PV consumes S^T C-layout regs directly as A-operand fragments.
__global__ __launch_bounds__(256, 2) void k_gemm_qkv(
    const unsigned short* __restrict__ xb, const unsigned short* __restrict__ Wb,
    const float* __restrict__ bq, const float* __restrict__ bk, const float* __restrict__ bv,
    unsigned short* __restrict__ Qb, unsigned short* __restrict__ Kb, unsigned short* __restrict__ Vtb) {
  __shared__ unsigned short As[128 * 32];
  __shared__ unsigned short Bs[128 * 32];
  const int tid = threadIdx.x;
  const int lane = tid & 63;
  const int w = tid >> 6;
  const int wm = w & 1;
  const int wn = w >> 1;
  const int z = blockIdx.z;
  const int m0 = blockIdx.y * 128;
  const int n0 = blockIdx.x * 128;
  const unsigned short* W = Wb + ((size_t)z << 20);

  const int srow = tid >> 2;          // 0..63
  const int sch = (tid & 3) << 3;     // 0,8,16,24 elements
  const size_t a0 = (size_t)(m0 + srow) * 1024 + sch;
  const size_t b0 = (size_t)(n0 + srow) * 1024 + sch;

  f32x4 zero4 = {0.f, 0.f, 0.f, 0.f};
  f32x4 acc[4][4];
#pragma unroll
  for (int i = 0; i < 4; ++i)
#pragma unroll
    for (int jj = 0; jj < 4; ++jj) acc[i][jj] = zero4;

  const int fr = lane & 15;
  const int fk = (lane >> 4) << 3;

  for (int kt = 0; kt < 32; ++kt) {
    const int ko = kt << 5;
    __syncthreads();
    gload16(xb + a0 + ko, As + tid * 8);
    gload16(xb + a0 + (size_t)65536 + ko, As + 2048 + tid * 8);
    gload16(W + b0 + ko, Bs + tid * 8);
    gload16(W + b0 + (size_t)65536 + ko, Bs + 2048 + tid * 8);
    __syncthreads();
    bf16x8 af[4], bfr[4];
#pragma unroll
    for (int mt = 0; mt < 4; ++mt)
      af[mt] = *(const bf16x8*)&As[(wm * 64 + mt * 16 + fr) * 32 + fk];
#pragma unroll
    for (int nt = 0; nt < 4; ++nt)
      bfr[nt] = *(const bf16x8*)&Bs[(wn * 64 + nt * 16 + fr) * 32 + fk];
#pragma unroll
    for (int mt = 0; mt < 4; ++mt)
#pragma unroll
      for (int nt = 0; nt < 4; ++nt)
        acc[mt][nt] = __builtin_amdgcn_mfma_f32_16x16x32_bf16(af[mt], bfr[nt], acc[mt][nt], 0, 0, 0);
  }

  const float* bias = (z == 0) ? bq : (z == 1) ? bk : bv;
  const float bsc = (z == 0) ? QSCALE : 1.0f;
  const int rg = (lane >> 4) << 2;
#pragma unroll
  for (int mt = 0; mt < 4; ++mt) {
    const int mb = m0 + wm * 64 + mt * 16 + rg;  // multiple of 4
    const int b = mb >> 11;
    const int s = mb & 2047;
#pragma unroll
    for (int nt = 0; nt < 4; ++nt) {
      const int n = n0 + wn * 64 + nt * 16 + fr;
      const float bvv = bias[n] * bsc;
      const int h = n >> 6;
      const int d = n & 63;
      if (z == 2) {
        u16x4 pk;
#pragma unroll
        for (int r = 0; r < 4; ++r) pk[r] = f2bf(acc[mt][nt][r] + bvv);
        const int pbase = (s & ~31) | ((s & 12) << 1) | ((s & 16) >> 2);
        *(u16x4*)&Vtb[(((size_t)(b * 16 + h) << 6) + d) * 2048 + pbase] = pk;
      } else {
        unsigned short* O = (z == 0) ? Qb : Kb;
#pragma unroll
        for (int r = 0; r < 4; ++r)
          O[(((size_t)(b * 16 + h) << 11) + s + r) * 64 + d] = f2bf(acc[mt][nt][r] + bvv);
      }
    }
  }
}

// ---------------- flash attention (S^T, no-max softmax, register P, 64q/wave) ----
// grid (8, 64): x = 256-row q-tile, y = b*16+h. Each wave: 64 queries x 128 keys/iter.
// Phase A: two qt-pairs of QK^T (kf shared per pair) -> exp2 -> pack held in regs.
// Phase B: one vf pass, each vf feeds 4 MFMAs (qt=0..3).
// launch_bounds(256,2): VGPR cap 256, model peak ~244 (r4 lesson: watch WRITE_SIZE for spills).
__global__ __launch_bounds__(256, 2) void k_flash(
    const unsigned short* __restrict__ Qb, const unsigned short* __restrict__ Kb,
    const unsigned short* __restrict__ Vtb, unsigned short* __restrict__ Ctx) {
  __shared__ unsigned short Ks[128 * 64];   // 16KB [key][64d], 3-bit chunk xor
  __shared__ unsigned short Vts[64 * 128];  // 16KB [d][128k_perm], 4-bit chunk xor
  const int tid = threadIdx.x;
  const int lane = tid & 63;
  const int wq = tid >> 6;       // wave id: query band wq*64
  const int fr = lane & 15;
  const int qd = lane >> 4;      // quad 0..3
  const int bh = blockIdx.y;
  const int q0 = blockIdx.x << 8;
  const size_t hoff = (size_t)bh << 17;  // 2048*64
  const unsigned short* Qh = Qb + hoff + ((size_t)q0 << 6);
  const unsigned short* Kh = Kb + hoff;
  const unsigned short* Vh = Vtb + hoff;

  // Q fragments: B[n=query][k=d]; row = wq*64+qt*16+fr, d = ds*32+qd*8..+7
  bf16x8 qf[4][2];
#pragma unroll
  for (int qt = 0; qt < 4; ++qt)
#pragma unroll
    for (int ds = 0; ds < 2; ++ds)
      qf[qt][ds] = *(const bf16x8*)&Qh[(wq * 64 + qt * 16 + fr) * 64 + ds * 32 + qd * 8];

  f32x4 zero4 = {0.f, 0.f, 0.f, 0.f};
  f32x4 o_acc[4][4];
  float l_p[4] = {0.f, 0.f, 0.f, 0.f};
#pragma unroll
  for (int qt = 0; qt < 4; ++qt)
#pragma unroll
    for (int dt = 0; dt < 4; ++dt) o_acc[qt][dt] = zero4;

  for (int j = 0; j < 16; ++j) {
    const int k0 = j << 7;
    __syncthreads();  // prior iter's Ks/Vts reads complete
#pragma unroll
    for (int p = 0; p < 4; ++p) {  // K tile: [128 key][64 d]
      int slot = p * 256 + tid;
      int kr = slot >> 3;
      int ch = slot & 7;
      gload16(Kh + (size_t)(k0 + kr) * 64 + ((ch ^ (kr & 7)) << 3), Ks + slot * 8);
    }
#pragma unroll
    for (int p = 0; p < 4; ++p) {  // V^T tile: [64 d][128 key_perm]
      int slot = p * 256 + tid;
      int dr = slot >> 4;
      int ch = slot & 15;
      gload16(Vh + (size_t)dr * 2048 + k0 + ((ch ^ (dr & 15)) << 3), Vts + slot * 8);
    }
    __syncthreads();  // staging visible

    unsigned int ppk[4][8][2];  // packed bf16 P, per qt

    // ---- Phase A: S^T = K·Q^T per qt-pair; exp2; pack ----
#pragma unroll
    for (int pr = 0; pr < 2; ++pr) {
      f32x4 st[2][8];
#pragma unroll
      for (int q2 = 0; q2 < 2; ++q2)
#pragma unroll
        for (int kt = 0; kt < 8; ++kt) st[q2][kt] = zero4;
#pragma unroll
      for (int kt = 0; kt < 8; ++kt) {
#pragma unroll
        for (int ds = 0; ds < 2; ++ds) {
          int key = kt * 16 + fr;
          int c = ds * 4 + qd;
          bf16x8 kf = *(const bf16x8*)&Ks[key * 64 + ((c ^ (key & 7)) << 3)];
          st[0][kt] = __builtin_amdgcn_mfma_f32_16x16x32_bf16(kf, qf[2 * pr][ds], st[0][kt], 0, 0, 0);
          st[1][kt] = __builtin_amdgcn_mfma_f32_16x16x32_bf16(kf, qf[2 * pr + 1][ds], st[1][kt], 0, 0, 0);
        }
      }
#pragma unroll
      for (int q2 = 0; q2 < 2; ++q2) {
        const int qt = 2 * pr + q2;
        float ps0 = 0.f, ps1 = 0.f;
#pragma unroll
        for (int kt = 0; kt < 8; ++kt) {
#pragma unroll
          for (int r = 0; r < 4; ++r) st[q2][kt][r] = __builtin_amdgcn_exp2f(st[q2][kt][r]);
          ps0 += st[q2][kt][0] + st[q2][kt][2];
          ps1 += st[q2][kt][1] + st[q2][kt][3];
          ppk[qt][kt][0] = pack2bf(st[q2][kt][0], st[q2][kt][1]);
          ppk[qt][kt][1] = pack2bf(st[q2][kt][2], st[q2][kt][3]);
        }
        l_p[qt] += ps0 + ps1;
      }
    }

    // ---- Phase B: O += P·V, vf shared across 4 qt ----
#pragma unroll
    for (int ks = 0; ks < 4; ++ks) {
      bf16x8 pf[4];
#pragma unroll
      for (int qt = 0; qt < 4; ++qt) {
        u32x4 pk;
        pk[0] = ppk[qt][2 * ks][0];
        pk[1] = ppk[qt][2 * ks][1];
        pk[2] = ppk[qt][2 * ks + 1][0];
        pk[3] = ppk[qt][2 * ks + 1][1];
        pf[qt] = __builtin_bit_cast(bf16x8, pk);
      }
#pragma unroll
      for (int dt = 0; dt < 4; ++dt) {
        int d = dt * 16 + fr;
        int c = ks * 4 + qd;
        bf16x8 vf = *(const bf16x8*)&Vts[d * 128 + ((c ^ (d & 15)) << 3)];
#pragma unroll
        for (int qt = 0; qt < 4; ++qt)
          o_acc[qt][dt] = __builtin_amdgcn_mfma_f32_16x16x32_bf16(pf[qt], vf, o_acc[qt][dt], 0, 0, 0);
      }
    }
  }

  // reduce l across the 4 lanes sharing each query (fr), once
  float l_red[4];
#pragma unroll
  for (int qt = 0; qt < 4; ++qt) {
    float lv = l_p[qt];
    lv += __shfl_xor(lv, 16);
    lv += __shfl_xor(lv, 32);
    l_red[qt] = lv;
  }

  // epilogue: normalize, write context [b][s][h*64+d] bf16
  const int b = bh >> 4;
  const int h = bh & 15;
#pragma unroll
  for (int qt = 0; qt < 4; ++qt) {
#pragma unroll
    for (int r = 0; r < 4; ++r) {
      float lv = __shfl(l_red[qt], qd * 4 + r);
      float rl = 1.0f / lv;
      int s = q0 + wq * 64 + qt * 16 + qd * 4 + r;
      size_t base = (((size_t)b * 2048 + s) << 10) + (h << 6);
#pragma unroll
      for (int dt = 0; dt < 4; ++dt) Ctx[base + dt * 16 + fr] = f2bf(o_acc[qt][dt][r] * rl);
    }
  }
}

// ---------------- output projection GEMM (f32 out) ----------------
__global__ __launch_bounds__(256, 2) void k_gemm_out(
    const unsigned short* __restrict__ Ctx, const unsigned short* __restrict__ Wo,
    const float* __restrict__ bo, float* __restrict__ out) {
  __shared__ unsigned short As[128 * 32];
  __shared__ unsigned short Bs[128 * 32];
  const int tid = threadIdx.x;
  const int lane = tid & 63;
  const int w = tid >> 6;
  const int wm = w & 1;
  const int wn = w >> 1;
  const int m0 = blockIdx.y * 128;
  const int n0 = blockIdx.x * 128;

  const int srow = tid >> 2;
  const int sch = (tid & 3) << 3;
  const size_t a0 = (size_t)(m0 + srow) * 1024 + sch;
  const size_t b0 = (size_t)(n0 + srow) * 1024 + sch;

  f32x4 zero4 = {0.f, 0.f, 0.f, 0.f};
  f32x4 acc[4][4];
#pragma unroll
  for (int i = 0; i < 4; ++i)
#pragma unroll
    for (int jj = 0; jj < 4; ++jj) acc[i][jj] = zero4;

  const int fr = lane & 15;
  const int fk = (lane >> 4) << 3;

  for (int kt = 0; kt < 32; ++kt) {
    const int ko = kt << 5;
    __syncthreads();
    gload16(Ctx + a0 + ko, As + tid * 8);
    gload16(Ctx + a0 + (size_t)65536 + ko, As + 2048 + tid * 8);
    gload16(Wo + b0 + ko, Bs + tid * 8);
    gload16(Wo + b0 + (size_t)65536 + ko, Bs + 2048 + tid * 8);
    __syncthreads();
    bf16x8 af[4], bfr[4];
#pragma unroll
    for (int mt = 0; mt < 4; ++mt)
      af[mt] = *(const bf16x8*)&As[(wm * 64 + mt * 16 + fr) * 32 + fk];
#pragma unroll
    for (int nt = 0; nt < 4; ++nt)
      bfr[nt] = *(const bf16x8*)&Bs[(wn * 64 + nt * 16 + fr) * 32 + fk];
#pragma unroll
    for (int mt = 0; mt < 4; ++mt)
#pragma unroll
      for (int nt = 0; nt < 4; ++nt)
        acc[mt][nt] = __builtin_amdgcn_mfma_f32_16x16x32_bf16(af[mt], bfr[nt], acc[mt][nt], 0, 0, 0);
  }

  const int rg = (lane >> 4) << 2;
#pragma unroll
  for (int mt = 0; mt < 4; ++mt) {
    const int mb = m0 + wm * 64 + mt * 16 + rg;
#pragma unroll
    for (int nt = 0; nt < 4; ++nt) {
      const int n = n0 + wn * 64 + nt * 16 + fr;
      const float bvv = bo[n];
#pragma unroll
      for (int r = 0; r < 4; ++r)
        out[(size_t)(mb + r) * 1024 + n] = acc[mt][nt][r] + bvv;
    }
  }
}

// ---------------- host ----------------
extern "C" void kernel_launch(void* const* d_in, const int* in_sizes, int n_in,
                              void* d_out, int out_size, void* d_ws, size_t ws_size,
                              hipStream_t stream) {
  (void)in_sizes; (void)n_in; (void)out_size; (void)ws_size;
  const float* x = (const float*)d_in[0];
  const float* Wq = (const float*)d_in[1];
  const float* bq = (const float*)d_in[2];
  const float* Wk = (const float*)d_in[3];
  const float* bk = (const float*)d_in[4];
  const float* Wv = (const float*)d_in[5];
  const float* bv = (const float*)d_in[6];
  const float* Wo = (const float*)d_in[7];
  const float* bo = (const float*)d_in[8];
  float* out = (float*)d_out;

  // workspace layout (bf16 as ushort); total 72 MB
  unsigned short* xb = (unsigned short*)d_ws;  // 8388608 el
  unsigned short* Wb = xb + 8388608;           // 4194304 el (q,k,v,o)
  unsigned short* Qb = Wb + 4194304;           // 8388608 el [b,h,s,d]
  unsigned short* Kb = Qb + 8388608;           // [b,h,s,d]
  unsigned short* Vtb = Kb + 8388608;          // [b,h,d,s_perm]
  unsigned short* Ctx = xb;                    // reuse xb (dead after k_gemm_qkv)

  k_cvt<<<12288, 256, 0, stream>>>(x, Wq, Wk, Wv, Wo, xb, Wb);
  k_gemm_qkv<<<dim3(8, 64, 3), 256, 0, stream>>>(xb, Wb, bq, bk, bv, Qb, Kb, Vtb);
  k_flash<<<dim3(8, 64), 256, 0, stream>>>(Qb, Kb, Vtb, Ctx);
  k_gemm_out<<<dim3(8, 64), 256, 0, stream>>>(Ctx, Wb + 3 * 1048576, bo, out);
}

// Round 7
// 286.869 us; speedup vs baseline: 1.0975x; 1.0975x over previous
//
#include <hip/hip_runtime.h>

// SelfAttention: B=4, S=2048, D=1024, H=16, Hd=64. f32 in/out, bf16 MFMA inside.

#define LOG2E 1.4426950408889634f
#define QSCALE (0.125f * LOG2E)   // 1/sqrt(64) * log2(e), folded into Wq/bq

typedef __bf16 bf16x8 __attribute__((ext_vector_type(8)));
typedef float f32x4 __attribute__((ext_vector_type(4)));
typedef unsigned short u16x4 __attribute__((ext_vector_type(4)));
typedef unsigned short u16x8 __attribute__((ext_vector_type(8)));
typedef unsigned int u32x4 __attribute__((ext_vector_type(4)));

__device__ __forceinline__ unsigned short f2bf(float f) {
  unsigned int u = __builtin_bit_cast(unsigned int, f);
  u += 0x7fffu + ((u >> 16) & 1u);   // RNE
  return (unsigned short)(u >> 16);
}

// pack bf16(a) low16, bf16(b) high16; RNE. v_bfe+v_add3 x2 + v_perm.
__device__ __forceinline__ unsigned int pack2bf(float a, float b) {
  unsigned int ua = __builtin_bit_cast(unsigned int, a);
  unsigned int ub = __builtin_bit_cast(unsigned int, b);
  ua += 0x7fffu + ((ua >> 16) & 1u);
  ub += 0x7fffu + ((ub >> 16) & 1u);
  return __builtin_amdgcn_perm(ub, ua, 0x07060302u);
}

typedef const __attribute__((address_space(1))) void* gptr_t;
typedef __attribute__((address_space(3))) void* lptr_t;
__device__ __forceinline__ void gload16(const void* g, void* l) {
  __builtin_amdgcn_global_load_lds((gptr_t)g, (lptr_t)l, 16, 0, 0);
}

// ---------------- merged convert kernel ----------------
__global__ __launch_bounds__(256) void k_cvt(const float* __restrict__ x,
                                             const float* __restrict__ Wq, const float* __restrict__ Wk,
                                             const float* __restrict__ Wv, const float* __restrict__ Wo,
                                             unsigned short* __restrict__ xb, unsigned short* __restrict__ Wb) {
  int gi = (blockIdx.x * 256 + threadIdx.x) * 4;
  if (gi < 8388608) {
    f32x4 v = *(const f32x4*)(x + gi);
    u16x4 o; o[0] = f2bf(v[0]); o[1] = f2bf(v[1]); o[2] = f2bf(v[2]); o[3] = f2bf(v[3]);
    *(u16x4*)(xb + gi) = o;
  } else {
    int i = gi - 8388608;
    int wsel = i >> 20;
    int loc = i & 1048575;
    const float* src = (wsel == 0) ? Wq : (wsel == 1) ? Wk : (wsel == 2) ? Wv : Wo;
    float sc = (wsel == 0) ? QSCALE : 1.0f;
    f32x4 v = *(const f32x4*)(src + loc);
    u16x4 o; o[0] = f2bf(v[0] * sc); o[1] = f2bf(v[1] * sc); o[2] = f2bf(v[2] * sc); o[3] = f2bf(v[3] * sc);
    *(u16x4*)(Wb + i) = o;
  }
}

// ---------------- QKV projection GEMM ----------------
// z=0: Q (pre-scaled) -> [b,h,s,d]; z=1: K -> [b,h,s,d];
// z=2: V -> [b,h,d,s_perm] (pos=8q+4h+r for s=16h+4q+r) so flash PV consumes
//      S^T C-layout regs directly as A-operand fragments.
__global__ __launch_bounds__(256, 2) void k_gemm_qkv(
    const unsigned short* __restrict__ xb, const unsigned short* __restrict__ Wb,
    const float* __restrict__ bq, const float* __restrict__ bk, const float* __restrict__ bv,
    unsigned short* __restrict__ Qb, unsigned short* __restrict__ Kb, unsigned short* __restrict__ Vtb) {
  __shared__ unsigned short As[128 * 32];
  __shared__ unsigned short Bs[128 * 32];
  const int tid = threadIdx.x;
  const int lane = tid & 63;
  const int w = tid >> 6;
  const int wm = w & 1;
  const int wn = w >> 1;
  const int z = blockIdx.z;
  const int m0 = blockIdx.y * 128;
  const int n0 = blockIdx.x * 128;
  const unsigned short* W = Wb + ((size_t)z << 20);

  const int srow = tid >> 2;
  const int sch = (tid & 3) << 3;
  const size_t a0 = (size_t)(m0 + srow) * 1024 + sch;
  const size_t b0 = (size_t)(n0 + srow) * 1024 + sch;

  f32x4 zero4 = {0.f, 0.f, 0.f, 0.f};
  f32x4 acc[4][4];
#pragma unroll
  for (int i = 0; i < 4; ++i)
#pragma unroll
    for (int jj = 0; jj < 4; ++jj) acc[i][jj] = zero4;

  const int fr = lane & 15;
  const int fk = (lane >> 4) << 3;

  for (int kt = 0; kt < 32; ++kt) {
    const int ko = kt << 5;
    __syncthreads();
    gload16(xb + a0 + ko, As + tid * 8);
    gload16(xb + a0 + (size_t)65536 + ko, As + 2048 + tid * 8);
    gload16(W + b0 + ko, Bs + tid * 8);
    gload16(W + b0 + (size_t)65536 + ko, Bs + 2048 + tid * 8);
    __syncthreads();
    bf16x8 af[4], bfr[4];
#pragma unroll
    for (int mt = 0; mt < 4; ++mt)
      af[mt] = *(const bf16x8*)&As[(wm * 64 + mt * 16 + fr) * 32 + fk];
#pragma unroll
    for (int nt = 0; nt < 4; ++nt)
      bfr[nt] = *(const bf16x8*)&Bs[(wn * 64 + nt * 16 + fr) * 32 + fk];
#pragma unroll
    for (int mt = 0; mt < 4; ++mt)
#pragma unroll
      for (int nt = 0; nt < 4; ++nt)
        acc[mt][nt] = __builtin_amdgcn_mfma_f32_16x16x32_bf16(af[mt], bfr[nt], acc[mt][nt], 0, 0, 0);
  }

  const float* bias = (z == 0) ? bq : (z == 1) ? bk : bv;
  const float bsc = (z == 0) ? QSCALE : 1.0f;
  const int rg = (lane >> 4) << 2;
#pragma unroll
  for (int mt = 0; mt < 4; ++mt) {
    const int mb = m0 + wm * 64 + mt * 16 + rg;
    const int b = mb >> 11;
    const int s = mb & 2047;
#pragma unroll
    for (int nt = 0; nt < 4; ++nt) {
      const int n = n0 + wn * 64 + nt * 16 + fr;
      const float bvv = bias[n] * bsc;
      const int h = n >> 6;
      const int d = n & 63;
      if (z == 2) {
        u16x4 pk;
#pragma unroll
        for (int r = 0; r < 4; ++r) pk[r] = f2bf(acc[mt][nt][r] + bvv);
        const int pbase = (s & ~31) | ((s & 12) << 1) | ((s & 16) >> 2);
        *(u16x4*)&Vtb[(((size_t)(b * 16 + h) << 6) + d) * 2048 + pbase] = pk;
      } else {
        unsigned short* O = (z == 0) ? Qb : Kb;
#pragma unroll
        for (int r = 0; r < 4; ++r)
          O[(((size_t)(b * 16 + h) << 11) + s + r) * 64 + d] = f2bf(acc[mt][nt][r] + bvv);
      }
    }
  }
}

// ---------------- flash attention (S^T, no-max softmax, register P, 32q/wave) ----
// r5 structure (r6's 64q/wave spilled: VGPR cap 128, 110MB scratch). New in r7:
// all j-invariant addressing hoisted out of the loop — 32 LDS read offsets in
// registers, 8 staging pointers strength-reduced (+= stride per iter).
__global__ __launch_bounds__(256, 3) void k_flash(
    const unsigned short* __restrict__ Qb, const unsigned short* __restrict__ Kb,
    const unsigned short* __restrict__ Vtb, unsigned short* __restrict__ Ctx) {
  __shared__ unsigned short Ks[128 * 64];   // 16KB [key][64d], 3-bit chunk xor
  __shared__ unsigned short Vts[64 * 128];  // 16KB [d][128k_perm], 4-bit chunk xor
  const int tid = threadIdx.x;
  const int lane = tid & 63;
  const int wq = tid >> 6;
  const int fr = lane & 15;
  const int qd = lane >> 4;
  const int bh = blockIdx.y;
  const int q0 = blockIdx.x << 7;
  const size_t hoff = (size_t)bh << 17;  // 2048*64
  const unsigned short* Qh = Qb + hoff + ((size_t)q0 << 6);

  // ---- hoisted staging addresses (advance by constant stride per j) ----
  const unsigned short* kg[4];
  const unsigned short* vg[4];
  unsigned short* kl[4];
  unsigned short* vl[4];
#pragma unroll
  for (int p = 0; p < 4; ++p) {
    int slot = p * 256 + tid;
    int kr = slot >> 3, ch = slot & 7;
    kg[p] = Kb + hoff + (size_t)kr * 64 + ((ch ^ (kr & 7)) << 3);
    kl[p] = Ks + slot * 8;
    int dr = slot >> 4, ch2 = slot & 15;
    vg[p] = Vtb + hoff + (size_t)dr * 2048 + ((ch2 ^ (dr & 15)) << 3);
    vl[p] = Vts + slot * 8;
  }

  // ---- hoisted LDS read element-offsets ----
  int kofs[8][2];
#pragma unroll
  for (int kt = 0; kt < 8; ++kt)
#pragma unroll
    for (int ds = 0; ds < 2; ++ds) {
      int key = kt * 16 + fr, c = ds * 4 + qd;
      kofs[kt][ds] = key * 64 + ((c ^ (key & 7)) << 3);
    }
  int vofs[4][4];
#pragma unroll
  for (int ks = 0; ks < 4; ++ks)
#pragma unroll
    for (int dt = 0; dt < 4; ++dt) {
      int d = dt * 16 + fr, c = ks * 4 + qd;
      vofs[ks][dt] = d * 128 + ((c ^ (d & 15)) << 3);
    }

  // Q fragments: B[n=query][k=d]; row = wq*32+qt*16+fr, d = ds*32+qd*8..+7
  bf16x8 qf[2][2];
#pragma unroll
  for (int qt = 0; qt < 2; ++qt)
#pragma unroll
    for (int ds = 0; ds < 2; ++ds)
      qf[qt][ds] = *(const bf16x8*)&Qh[(wq * 32 + qt * 16 + fr) * 64 + ds * 32 + qd * 8];

  f32x4 zero4 = {0.f, 0.f, 0.f, 0.f};
  f32x4 o_acc[2][4];
  float l_p[2] = {0.f, 0.f};
#pragma unroll
  for (int mt = 0; mt < 2; ++mt)
#pragma unroll
    for (int dt = 0; dt < 4; ++dt) o_acc[mt][dt] = zero4;

  for (int j = 0; j < 16; ++j) {
    __syncthreads();  // prior iter's Ks/Vts reads complete
#pragma unroll
    for (int p = 0; p < 4; ++p) gload16(kg[p], kl[p]);
#pragma unroll
    for (int p = 0; p < 4; ++p) gload16(vg[p], vl[p]);
#pragma unroll
    for (int p = 0; p < 4; ++p) { kg[p] += 128 * 64; vg[p] += 128; }
    __syncthreads();  // staging visible

    // ---- S^T = K · Q^T : D[row=key][col=query] ----
    f32x4 st[2][8];
#pragma unroll
    for (int qt = 0; qt < 2; ++qt)
#pragma unroll
      for (int kt = 0; kt < 8; ++kt) st[qt][kt] = zero4;
#pragma unroll
    for (int kt = 0; kt < 8; ++kt) {
#pragma unroll
      for (int ds = 0; ds < 2; ++ds) {
        bf16x8 kf = *(const bf16x8*)&Ks[kofs[kt][ds]];
        st[0][kt] = __builtin_amdgcn_mfma_f32_16x16x32_bf16(kf, qf[0][ds], st[0][kt], 0, 0, 0);
        st[1][kt] = __builtin_amdgcn_mfma_f32_16x16x32_bf16(kf, qf[1][ds], st[1][kt], 0, 0, 0);
      }
    }

    // ---- p = exp2(s) raw; accumulate l in-lane ----
#pragma unroll
    for (int qt = 0; qt < 2; ++qt) {
      float ps0 = 0.f, ps1 = 0.f;
#pragma unroll
      for (int kt = 0; kt < 8; ++kt) {
#pragma unroll
        for (int r = 0; r < 4; ++r) st[qt][kt][r] = __builtin_amdgcn_exp2f(st[qt][kt][r]);
        ps0 += st[qt][kt][0] + st[qt][kt][2];
        ps1 += st[qt][kt][1] + st[qt][kt][3];
      }
      l_p[qt] += ps0 + ps1;
    }

    // ---- O += P · V : A-fragments straight from st regs (permuted-key order) ----
#pragma unroll
    for (int ks = 0; ks < 4; ++ks) {
      bf16x8 pf[2];
#pragma unroll
      for (int mt = 0; mt < 2; ++mt) {
        u32x4 pk;
        pk[0] = pack2bf(st[mt][2 * ks][0], st[mt][2 * ks][1]);
        pk[1] = pack2bf(st[mt][2 * ks][2], st[mt][2 * ks][3]);
        pk[2] = pack2bf(st[mt][2 * ks + 1][0], st[mt][2 * ks + 1][1]);
        pk[3] = pack2bf(st[mt][2 * ks + 1][2], st[mt][2 * ks + 1][3]);
        pf[mt] = __builtin_bit_cast(bf16x8, pk);
      }
#pragma unroll
      for (int dt = 0; dt < 4; ++dt) {
        bf16x8 vf = *(const bf16x8*)&Vts[vofs[ks][dt]];
#pragma unroll
        for (int mt = 0; mt < 2; ++mt)
          o_acc[mt][dt] = __builtin_amdgcn_mfma_f32_16x16x32_bf16(pf[mt], vf, o_acc[mt][dt], 0, 0, 0);
      }
    }
  }

  // reduce l across the 4 lanes sharing each query (fr), once
  float l_red[2];
#pragma unroll
  for (int mt = 0; mt < 2; ++mt) {
    float lv = l_p[mt];
    lv += __shfl_xor(lv, 16);
    lv += __shfl_xor(lv, 32);
    l_red[mt] = lv;
  }

  // epilogue: normalize, write context [b][s][h*64+d] bf16
  const int b = bh >> 4;
  const int h = bh & 15;
#pragma unroll
  for (int mt = 0; mt < 2; ++mt) {
#pragma unroll
    for (int r = 0; r < 4; ++r) {
      float lv = __shfl(l_red[mt], qd * 4 + r);
      float rl = 1.0f / lv;
      int s = q0 + wq * 32 + mt * 16 + qd * 4 + r;
      size_t base = (((size_t)b * 2048 + s) << 10) + (h << 6);
#pragma unroll
      for (int dt = 0; dt < 4; ++dt) Ctx[base + dt * 16 + fr] = f2bf(o_acc[mt][dt][r] * rl);
    }
  }
}

// ---------------- output projection GEMM (f32 out) ----------------
__global__ __launch_bounds__(256, 2) void k_gemm_out(
    const unsigned short* __restrict__ Ctx, const unsigned short* __restrict__ Wo,
    const float* __restrict__ bo, float* __restrict__ out) {
  __shared__ unsigned short As[128 * 32];
  __shared__ unsigned short Bs[128 * 32];
  const int tid = threadIdx.x;
  const int lane = tid & 63;
  const int w = tid >> 6;
  const int wm = w & 1;
  const int wn = w >> 1;
  const int m0 = blockIdx.y * 128;
  const int n0 = blockIdx.x * 128;

  const int srow = tid >> 2;
  const int sch = (tid & 3) << 3;
  const size_t a0 = (size_t)(m0 + srow) * 1024 + sch;
  const size_t b0 = (size_t)(n0 + srow) * 1024 + sch;

  f32x4 zero4 = {0.f, 0.f, 0.f, 0.f};
  f32x4 acc[4][4];
#pragma unroll
  for (int i = 0; i < 4; ++i)
#pragma unroll
    for (int jj = 0; jj < 4; ++jj) acc[i][jj] = zero4;

  const int fr = lane & 15;
  const int fk = (lane >> 4) << 3;

  for (int kt = 0; kt < 32; ++kt) {
    const int ko = kt << 5;
    __syncthreads();
    gload16(Ctx + a0 + ko, As + tid * 8);
    gload16(Ctx + a0 + (size_t)65536 + ko, As + 2048 + tid * 8);
    gload16(Wo + b0 + ko, Bs + tid * 8);
    gload16(Wo + b0 + (size_t)65536 + ko, Bs + 2048 + tid * 8);
    __syncthreads();
    bf16x8 af[4], bfr[4];
#pragma unroll
    for (int mt = 0; mt < 4; ++mt)
      af[mt] = *(const bf16x8*)&As[(wm * 64 + mt * 16 + fr) * 32 + fk];
#pragma unroll
    for (int nt = 0; nt < 4; ++nt)
      bfr[nt] = *(const bf16x8*)&Bs[(wn * 64 + nt * 16 + fr) * 32 + fk];
#pragma unroll
    for (int mt = 0; mt < 4; ++mt)
#pragma unroll
      for (int nt = 0; nt < 4; ++nt)
        acc[mt][nt] = __builtin_amdgcn_mfma_f32_16x16x32_bf16(af[mt], bfr[nt], acc[mt][nt], 0, 0, 0);
  }

  const int rg = (lane >> 4) << 2;
#pragma unroll
  for (int mt = 0; mt < 4; ++mt) {
    const int mb = m0 + wm * 64 + mt * 16 + rg;
#pragma unroll
    for (int nt = 0; nt < 4; ++nt) {
      const int n = n0 + wn * 64 + nt * 16 + fr;
      const float bvv = bo[n];
#pragma unroll
      for (int r = 0; r < 4; ++r)
        out[(size_t)(mb + r) * 1024 + n] = acc[mt][nt][r] + bvv;
    }
  }
}

// ---------------- host ----------------
extern "C" void kernel_launch(void* const* d_in, const int* in_sizes, int n_in,
                              void* d_out, int out_size, void* d_ws, size_t ws_size,
                              hipStream_t stream) {
  (void)in_sizes; (void)n_in; (void)out_size; (void)ws_size;
  const float* x = (const float*)d_in[0];
  const float* Wq = (const float*)d_in[1];
  const float* bq = (const float*)d_in[2];
  const float* Wk = (const float*)d_in[3];
  const float* bk = (const float*)d_in[4];
  const float* Wv = (const float*)d_in[5];
  const float* bv = (const float*)d_in[6];
  const float* Wo = (const float*)d_in[7];
  const float* bo = (const float*)d_in[8];
  float* out = (float*)d_out;

  unsigned short* xb = (unsigned short*)d_ws;  // 8388608 el
  unsigned short* Wb = xb + 8388608;           // 4194304 el (q,k,v,o)
  unsigned short* Qb = Wb + 4194304;           // [b,h,s,d]
  unsigned short* Kb = Qb + 8388608;           // [b,h,s,d]
  unsigned short* Vtb = Kb + 8388608;          // [b,h,d,s_perm]
  unsigned short* Ctx = xb;                    // reuse xb (dead after k_gemm_qkv)

  k_cvt<<<12288, 256, 0, stream>>>(x, Wq, Wk, Wv, Wo, xb, Wb);
  k_gemm_qkv<<<dim3(8, 64, 3), 256, 0, stream>>>(xb, Wb, bq, bk, bv, Qb, Kb, Vtb);
  k_flash<<<dim3(16, 64), 256, 0, stream>>>(Qb, Kb, Vtb, Ctx);
  k_gemm_out<<<dim3(8, 64), 256, 0, stream>>>(Ctx, Wb + 3 * 1048576, bo, out);
}